// Round 3
// baseline (326.619 us; speedup 1.0000x reference)
//
#include <hip/hip_runtime.h>

// Problem constants (match reference)
#define B_  16
#define N_  65536
#define G_  64
#define M_  (N_ + G_)      // 65600 rois per batch (rois + appended gt)
#define R_  128            // ROIS_PER_IMAGE
#define FGP 32             // FG_PER_IMAGE
#define NB_ 8192           // buckets for rank selection over u_perm in [0,1)

// ---------------------------------------------------------------------------
// K0: precompute GT table, SoA [b][5][G]: x1,y1,x2,y2,area with gt_zero folded
//     in as poisoned coords (iw clamps to 0 -> inter == 0 -> rational q == 0,
//     exactly matching reference's post-divide where(gt_zero, 0, ov)).
// ---------------------------------------------------------------------------
__global__ void prep_kernel(const float* __restrict__ gt_boxes,
                            float* __restrict__ gtp)
{
    int t = blockIdx.x * blockDim.x + threadIdx.x;
    if (t >= B_ * G_) return;
    int b = t / G_, j = t % G_;
    const float* g = gt_boxes + t * 6;
    float x1 = g[0], y1 = g[1], x2 = g[2], y2 = g[3];
    float gw = x2 - x1 + 1.0f, gh = y2 - y1 + 1.0f;
    float area = gw * gh;
    bool gz = (gw == 1.0f) && (gh == 1.0f);
    float* o = gtp + b * 5 * G_;
    o[0 * G_ + j] = gz ?  3.0e8f : x1;
    o[1 * G_ + j] = gz ?  3.0e8f : y1;
    o[2 * G_ + j] = gz ? -3.0e8f : x2;
    o[3 * G_ + j] = gz ? -3.0e8f : y2;
    o[4 * G_ + j] = area;            // =1.0 for gz; denom stays positive
}

// ---------------------------------------------------------------------------
// K1: divide-free IoU max/argmax.
//   Pass 1: rational running max via exact f64 cross-products (no VCC chains).
//   Epilogue: ONE IEEE f32 divide -> bit-exact reference max value.
//   Pass 2: first j with q_j in best's rounding interval == reference argmax.
// ---------------------------------------------------------------------------
__global__ void iou_kernel(const float* __restrict__ all_rois,
                           const float* __restrict__ gt_boxes,
                           const float* __restrict__ gtp,
                           const float* __restrict__ u_perm,
                           float* __restrict__ max_ov,
                           int*   __restrict__ gt_assign,
                           int*   __restrict__ fg_cnt,
                           int*   __restrict__ bg_cnt,
                           int*   __restrict__ hist)
{
    const int b = blockIdx.y;
    const int i = blockIdx.x * blockDim.x + threadIdx.x;
    if (i >= M_) return;

    float x1, y1, x2, y2;
    if (i < N_) {
        const float* p = all_rois + ((size_t)b * N_ + i) * 5;
        x1 = p[1]; y1 = p[2]; x2 = p[3]; y2 = p[4];
    } else {
        const float* p = gt_boxes + (b * G_ + (i - N_)) * 6;
        x1 = p[0]; y1 = p[1]; x2 = p[2]; y2 = p[3];
    }
    float aw = x2 - x1 + 1.0f, ah = y2 - y1 + 1.0f;
    float area_a = aw * ah;
    bool  a_zero = (aw == 1.0f) && (ah == 1.0f);

    const float* gp = gtp + b * 5 * G_;   // block-uniform base -> scalar loads

    // Pass 1: rational max (strict >, keeps first among rational ties)
    double ibd = -1.0, ubd = 1.0;         // best = -1/1 so j=0 always wins
    int    bi  = 0;
    #pragma unroll 8
    for (int j = 0; j < G_; ++j) {
        float iw = fmaxf(fminf(x2, gp[2 * G_ + j]) - fmaxf(x1, gp[0 * G_ + j]) + 1.0f, 0.0f);
        float ih = fmaxf(fminf(y2, gp[3 * G_ + j]) - fmaxf(y1, gp[1 * G_ + j]) + 1.0f, 0.0f);
        float inter = iw * ih;
        float uni   = area_a + gp[4 * G_ + j] - inter;   // > 0 always
        double id = (double)inter, ud = (double)uni;     // exact
        if (id * ubd > ibd * ud) {                       // exact 48-bit products
            ibd = id; ubd = ud; bi = j;
        }
    }

    float best;
    if (a_zero) {
        best = -1.0f; bi = 0;                            // a_zero overrides all
    } else {
        float ibf = (float)ibd, ubf = (float)ubd;        // exact (were f32)
        best = ibf / ubf;                                // ONE IEEE f32 divide
        if (best > 0.0f) {
            // Pass 2: reference argmax = first j with rounded(q_j) == best.
            // Since q_j <= q_bi <= hi for all j, the test is just q_j >= lo:
            //   inter_j >= lo * union_j   (lo*union exact: 25x24 bits < 53)
            unsigned vb = __float_as_uint(best);
            double lo = ((double)best + (double)__uint_as_float(vb - 1u)) * 0.5;
            bool incl = ((vb & 1u) == 0u);               // round-half-even edge
            int first = bi;
            #pragma unroll 8
            for (int j = 0; j < G_; ++j) {
                float iw = fmaxf(fminf(x2, gp[2 * G_ + j]) - fmaxf(x1, gp[0 * G_ + j]) + 1.0f, 0.0f);
                float ih = fmaxf(fminf(y2, gp[3 * G_ + j]) - fmaxf(y1, gp[1 * G_ + j]) + 1.0f, 0.0f);
                float inter = iw * ih;
                float uni   = area_a + gp[4 * G_ + j] - inter;
                double id = (double)inter;
                double t  = lo * (double)uni;
                bool ok = incl ? (id >= t) : (id > t);
                if (ok && j < first) first = j;
            }
            bi = first;
        } else {
            bi = 0;   // best == +0.0 -> every q_j == 0 -> first argmax is 0
        }
    }

    max_ov   [(size_t)b * M_ + i] = best;
    gt_assign[(size_t)b * M_ + i] = bi;

    bool fg = best >= 0.7f;
    bool bg = best < 0.3f;   // == ((mo<0.3)&(mo>=0)) | (mo<0) given mo in {-1}∪[0,1]
    if (fg) atomicAdd(&fg_cnt[b], 1);
    if (bg) atomicAdd(&bg_cnt[b], 1);
    int cls = fg ? 0 : (bg ? 1 : -1);
    if (cls >= 0) {
        float u = u_perm[(size_t)b * M_ + i];
        int bucket = (int)(u * (float)NB_);              // monotone in u
        bucket = min(max(bucket, 0), NB_ - 1);
        atomicAdd(&hist[(b * 2 + cls) * NB_ + bucket], 1);
    }
}

// ---------------------------------------------------------------------------
// K2: exclusive prefix sum of each (batch,class) histogram, in place
// ---------------------------------------------------------------------------
__global__ void scan_kernel(int* __restrict__ hist)
{
    __shared__ int s[NB_];
    __shared__ int tot[256];
    int* h = hist + blockIdx.x * NB_;
    const int t = threadIdx.x;           // 256 threads
    for (int k = t; k < NB_; k += 256) s[k] = h[k];
    __syncthreads();
    const int base = t * 32;
    int run = 0;
    for (int kk = 0; kk < 32; ++kk) { int v = s[base + kk]; s[base + kk] = run; run += v; }
    tot[t] = run;
    __syncthreads();
    if (t == 0) {
        int acc = 0;
        for (int q = 0; q < 256; ++q) { int v = tot[q]; tot[q] = acc; acc += v; }
    }
    __syncthreads();
    const int off = tot[t];
    for (int kk = 0; kk < 32; ++kk) h[base + kk] = s[base + kk] + off;
}

// ---------------------------------------------------------------------------
// K3: scatter element indices into bucket-grouped storage
// ---------------------------------------------------------------------------
__global__ void scatter_kernel(const float* __restrict__ u_perm,
                               const float* __restrict__ max_ov,
                               const int*  __restrict__ prefix,
                               int*        __restrict__ fill,
                               int*        __restrict__ buckets)
{
    const int b = blockIdx.y;
    const int i = blockIdx.x * blockDim.x + threadIdx.x;
    if (i >= M_) return;
    float mo = max_ov[(size_t)b * M_ + i];
    bool fg = mo >= 0.7f, bg = mo < 0.3f;
    int cls = fg ? 0 : (bg ? 1 : -1);
    if (cls < 0) return;
    float u = u_perm[(size_t)b * M_ + i];
    int bucket = min(max((int)(u * (float)NB_), 0), NB_ - 1);
    int hidx = (b * 2 + cls) * NB_ + bucket;
    int p = prefix[hidx] + atomicAdd(&fill[hidx], 1);
    buckets[(size_t)(b * 2 + cls) * M_ + p] = i;
}

// ---------------------------------------------------------------------------
// K4: per-(batch,pos) rank selection + gather outputs
// ---------------------------------------------------------------------------
__global__ void sample_kernel(const float* __restrict__ all_rois,
                              const float* __restrict__ gt_boxes,
                              const float* __restrict__ u_perm,
                              const float* __restrict__ u_fg,
                              const float* __restrict__ u_bg,
                              const int*  __restrict__ fg_cnt,
                              const int*  __restrict__ bg_cnt,
                              const int*  __restrict__ prefix,
                              const int*  __restrict__ fill,
                              const int*  __restrict__ buckets,
                              const int*  __restrict__ gt_assign,
                              float*      __restrict__ out)
{
    const int b   = blockIdx.x;
    const int pos = threadIdx.x;   // 128 threads
    const int fgn = fg_cnt[b];
    const int bgn = bg_cnt[b];
    const bool both    = (fgn > 0) && (bgn > 0);
    const bool only_fg = (fgn > 0) && (bgn == 0);
    const int fg_this  = both ? min(FGP, fgn) : (only_fg ? R_ : 0);
    const bool is_fg   = pos < fg_this;

    int cls, rank, cnum;
    if (is_fg) {
        cls = 0; cnum = fgn;
        if (only_fg) {
            float uf = u_fg[b * R_ + pos];
            int kk = (int)(uf * (float)fgn);               // trunc toward zero
            rank = min(max(kk, 0), max(fgn - 1, 0));
        } else {
            rank = pos;
        }
    } else {
        cls = 1; cnum = bgn;
        float ub = u_bg[b * R_ + pos];
        int kk = (int)(ub * (float)bgn);
        rank = min(max(kk, 0), max(bgn - 1, 0));
    }

    int keep = 0;  // bg_num==0 edge: argsort(all 2.0, stable)[0] == 0
    if (cnum > 0) {
        const int* pref = prefix + (b * 2 + cls) * NB_;
        const int* fl   = fill   + (b * 2 + cls) * NB_;
        // largest j with pref[j] <= rank  (never lands on an empty bucket)
        int lo = 0, hi = NB_ - 1;
        while (lo < hi) {
            int mid = (lo + hi + 1) >> 1;
            if (pref[mid] <= rank) lo = mid; else hi = mid - 1;
        }
        const int bucket = lo;
        const int r      = rank - pref[bucket];
        const int cnt    = fl[bucket];
        const int*   be  = buckets + (size_t)(b * 2 + cls) * M_ + pref[bucket];
        const float* up  = u_perm + (size_t)b * M_;
        // r-th smallest by (u, idx): stable-argsort semantics, order independent
        for (int t2 = 0; t2 < cnt; ++t2) {
            int it = be[t2]; float ut = up[it];
            int rk = 0;
            for (int s2 = 0; s2 < cnt; ++s2) {
                if (s2 == t2) continue;
                int is2 = be[s2]; float us = up[is2];
                if (us < ut || (us == ut && is2 < it)) rk++;
            }
            if (rk == r) { keep = it; break; }
        }
    }

    // gather roi
    float ox1, oy1, ox2, oy2;
    if (keep < N_) {
        const float* p = all_rois + ((size_t)b * N_ + keep) * 5;
        ox1 = p[1]; oy1 = p[2]; ox2 = p[3]; oy2 = p[4];
    } else {
        const float* p = gt_boxes + (b * G_ + (keep - N_)) * 6;
        ox1 = p[0]; oy1 = p[1]; ox2 = p[2]; oy2 = p[3];
    }
    float* ro = out + ((size_t)b * R_ + pos) * 5;
    ro[0] = (float)b; ro[1] = ox1; ro[2] = oy1; ro[3] = ox2; ro[4] = oy2;

    float lab = 0.0f, tidv = -1.0f;
    if (is_fg) {
        int ga = gt_assign[(size_t)b * M_ + keep];
        lab  = gt_boxes[(b * G_ + ga) * 6 + 4];
        tidv = gt_boxes[(b * G_ + ga) * 6 + 5];
    }
    float* olab = out + (size_t)B_ * R_ * 5;
    float* otid = olab + (size_t)B_ * R_;
    olab[b * R_ + pos] = lab;
    otid[b * R_ + pos] = tidv;
}

// ---------------------------------------------------------------------------
extern "C" void kernel_launch(void* const* d_in, const int* in_sizes, int n_in,
                              void* d_out, int out_size, void* d_ws, size_t ws_size,
                              hipStream_t stream)
{
    const float* all_rois = (const float*)d_in[0];
    const float* gt_boxes = (const float*)d_in[1];
    const float* u_perm   = (const float*)d_in[2];
    const float* u_fg     = (const float*)d_in[3];
    const float* u_bg     = (const float*)d_in[4];
    float* out = (float*)d_out;

    // workspace layout (ints unless noted); total ~21 MB
    int* fg_cnt  = (int*)d_ws;                      // 16
    int* bg_cnt  = fg_cnt + 16;                     // 16
    int* hist    = bg_cnt + 16;                     // B*2*NB  (prefix after K2)
    int* fill    = hist + B_ * 2 * NB_;             // B*2*NB
    float* max_ov = (float*)(fill + B_ * 2 * NB_);  // B*M floats
    int* ga      = (int*)(max_ov + (size_t)B_ * M_);// B*M
    int* buckets = ga + (size_t)B_ * M_;            // B*2*M
    float* gtp   = (float*)(buckets + (size_t)B_ * 2 * M_);  // B*5*G floats

    // zero counters + hist + fill (contiguous at the front)
    size_t zero_bytes = (size_t)(32 + 2 * B_ * 2 * NB_) * sizeof(int);
    hipMemsetAsync(d_ws, 0, zero_bytes, stream);

    prep_kernel<<<(B_ * G_ + 255) / 256, 256, 0, stream>>>(gt_boxes, gtp);

    dim3 grid1((M_ + 255) / 256, B_);
    iou_kernel<<<grid1, 256, 0, stream>>>(all_rois, gt_boxes, gtp, u_perm,
                                          max_ov, ga, fg_cnt, bg_cnt, hist);
    scan_kernel<<<B_ * 2, 256, 0, stream>>>(hist);
    scatter_kernel<<<grid1, 256, 0, stream>>>(u_perm, max_ov, hist, fill, buckets);
    sample_kernel<<<16, R_, 0, stream>>>(all_rois, gt_boxes, u_perm, u_fg, u_bg,
                                         fg_cnt, bg_cnt, hist, fill, buckets, ga, out);
}

// Round 4
// 162.811 us; speedup vs baseline: 2.0061x; 2.0061x over previous
//
#include <hip/hip_runtime.h>

// Problem constants (match reference)
#define B_  16
#define N_  65536
#define G_  64
#define M_  (N_ + G_)      // 65600 rois per batch (rois + appended gt)
#define R_  128            // ROIS_PER_IMAGE
#define FGP 32             // FG_PER_IMAGE
#define NB_ 8192           // buckets for rank selection over u_perm in [0,1)

// ---------------------------------------------------------------------------
// K0: precompute GT table, SoA [b][5][G]: x1,y1,x2,y2,area with gt_zero folded
//     in as poisoned coords (iw clamps to 0 -> inter==0 -> ov == +0.0 exactly,
//     matching reference's where(gt_zero, 0, ov)).
// ---------------------------------------------------------------------------
__global__ void prep_kernel(const float* __restrict__ gt_boxes,
                            float* __restrict__ gtp)
{
    int t = blockIdx.x * blockDim.x + threadIdx.x;
    if (t >= B_ * G_) return;
    int b = t / G_, j = t % G_;
    const float* g = gt_boxes + t * 6;
    float x1 = g[0], y1 = g[1], x2 = g[2], y2 = g[3];
    float gw = x2 - x1 + 1.0f, gh = y2 - y1 + 1.0f;
    float area = gw * gh;
    bool gz = (gw == 1.0f) && (gh == 1.0f);
    float* o = gtp + b * 5 * G_;
    o[0 * G_ + j] = gz ?  3.0e8f : x1;
    o[1 * G_ + j] = gz ?  3.0e8f : y1;
    o[2 * G_ + j] = gz ? -3.0e8f : x2;
    o[3 * G_ + j] = gz ? -3.0e8f : y2;
    o[4 * G_ + j] = area;            // =1.0 for gz; denom stays positive
}

// ---------------------------------------------------------------------------
// K1: per-roi IoU max/argmax + histogram. NO hot-address atomics: fg/bg totals
//     are derived later from the histogram totals in scan_kernel.
// ---------------------------------------------------------------------------
__global__ void iou_kernel(const float* __restrict__ all_rois,
                           const float* __restrict__ gt_boxes,
                           const float* __restrict__ gtp,
                           const float* __restrict__ u_perm,
                           float* __restrict__ max_ov,
                           int*   __restrict__ gt_assign,
                           int*   __restrict__ hist)
{
    const int b = blockIdx.y;
    const int i = blockIdx.x * blockDim.x + threadIdx.x;
    if (i >= M_) return;

    float x1, y1, x2, y2;
    if (i < N_) {
        const float* p = all_rois + ((size_t)b * N_ + i) * 5;
        x1 = p[1]; y1 = p[2]; x2 = p[3]; y2 = p[4];
    } else {
        const float* p = gt_boxes + (b * G_ + (i - N_)) * 6;
        x1 = p[0]; y1 = p[1]; x2 = p[2]; y2 = p[3];
    }
    float aw = x2 - x1 + 1.0f, ah = y2 - y1 + 1.0f;
    float area_a = aw * ah;
    bool  a_zero = (aw == 1.0f) && (ah == 1.0f);

    const float* gp = gtp + b * 5 * G_;   // block-uniform base -> scalar loads
    float best = -1e30f;
    int   bi   = 0;
    #pragma unroll 16
    for (int j = 0; j < G_; ++j) {
        float iw = fminf(x2, gp[2 * G_ + j]) - fmaxf(x1, gp[0 * G_ + j]) + 1.0f;
        float ih = fminf(y2, gp[3 * G_ + j]) - fmaxf(y1, gp[1 * G_ + j]) + 1.0f;
        iw = fmaxf(iw, 0.0f);
        ih = fmaxf(ih, 0.0f);
        float inter = iw * ih;
        float ov = inter / (area_a + gp[4 * G_ + j] - inter);  // IEEE div
        if (ov > best) { best = ov; bi = j; }                  // first-max
    }
    if (a_zero) { best = -1.0f; bi = 0; }                      // a_zero overrides

    max_ov   [(size_t)b * M_ + i] = best;
    gt_assign[(size_t)b * M_ + i] = bi;

    bool fg = best >= 0.7f;
    bool bg = best < 0.3f;   // == ((mo<0.3)&(mo>=0)) | (mo<0) given mo in {-1}∪[0,1]
    int cls = fg ? 0 : (bg ? 1 : -1);
    if (cls >= 0) {
        float u = u_perm[(size_t)b * M_ + i];
        int bucket = (int)(u * (float)NB_);              // monotone in u
        bucket = min(max(bucket, 0), NB_ - 1);
        atomicAdd(&hist[(b * 2 + cls) * NB_ + bucket], 1);  // scattered: 16K lines
    }
}

// ---------------------------------------------------------------------------
// K2: exclusive prefix sum of each (batch,class) histogram, in place.
//     Also emits the row total -> cnt[row]  (this IS fg_num / bg_num).
// ---------------------------------------------------------------------------
__global__ void scan_kernel(int* __restrict__ hist, int* __restrict__ cnt)
{
    __shared__ int s[NB_];
    __shared__ int tot[256];
    int* h = hist + blockIdx.x * NB_;
    const int t = threadIdx.x;           // 256 threads
    for (int k = t; k < NB_; k += 256) s[k] = h[k];
    __syncthreads();
    const int base = t * 32;
    int run = 0;
    for (int kk = 0; kk < 32; ++kk) { int v = s[base + kk]; s[base + kk] = run; run += v; }
    tot[t] = run;
    __syncthreads();
    if (t == 0) {
        int acc = 0;
        for (int q = 0; q < 256; ++q) { int v = tot[q]; tot[q] = acc; acc += v; }
        cnt[blockIdx.x] = acc;           // row total = class count for this batch
    }
    __syncthreads();
    const int off = tot[t];
    for (int kk = 0; kk < 32; ++kk) h[base + kk] = s[base + kk] + off;
}

// ---------------------------------------------------------------------------
// K3: scatter element indices into bucket-grouped storage
// ---------------------------------------------------------------------------
__global__ void scatter_kernel(const float* __restrict__ u_perm,
                               const float* __restrict__ max_ov,
                               const int*  __restrict__ prefix,
                               int*        __restrict__ fill,
                               int*        __restrict__ buckets)
{
    const int b = blockIdx.y;
    const int i = blockIdx.x * blockDim.x + threadIdx.x;
    if (i >= M_) return;
    float mo = max_ov[(size_t)b * M_ + i];
    bool fg = mo >= 0.7f, bg = mo < 0.3f;
    int cls = fg ? 0 : (bg ? 1 : -1);
    if (cls < 0) return;
    float u = u_perm[(size_t)b * M_ + i];
    int bucket = min(max((int)(u * (float)NB_), 0), NB_ - 1);
    int hidx = (b * 2 + cls) * NB_ + bucket;
    int p = prefix[hidx] + atomicAdd(&fill[hidx], 1);
    buckets[(size_t)(b * 2 + cls) * M_ + p] = i;
}

// ---------------------------------------------------------------------------
// K4: per-(batch,pos) rank selection + gather outputs
// ---------------------------------------------------------------------------
__global__ void sample_kernel(const float* __restrict__ all_rois,
                              const float* __restrict__ gt_boxes,
                              const float* __restrict__ u_perm,
                              const float* __restrict__ u_fg,
                              const float* __restrict__ u_bg,
                              const int*  __restrict__ cnt,
                              const int*  __restrict__ prefix,
                              const int*  __restrict__ fill,
                              const int*  __restrict__ buckets,
                              const int*  __restrict__ gt_assign,
                              float*      __restrict__ out)
{
    const int b   = blockIdx.x;
    const int pos = threadIdx.x;   // 128 threads
    const int fgn = cnt[b * 2 + 0];
    const int bgn = cnt[b * 2 + 1];
    const bool both    = (fgn > 0) && (bgn > 0);
    const bool only_fg = (fgn > 0) && (bgn == 0);
    const int fg_this  = both ? min(FGP, fgn) : (only_fg ? R_ : 0);
    const bool is_fg   = pos < fg_this;

    int cls, rank, cnum;
    if (is_fg) {
        cls = 0; cnum = fgn;
        if (only_fg) {
            float uf = u_fg[b * R_ + pos];
            int kk = (int)(uf * (float)fgn);               // trunc toward zero
            rank = min(max(kk, 0), max(fgn - 1, 0));
        } else {
            rank = pos;
        }
    } else {
        cls = 1; cnum = bgn;
        float ub = u_bg[b * R_ + pos];
        int kk = (int)(ub * (float)bgn);
        rank = min(max(kk, 0), max(bgn - 1, 0));
    }

    int keep = 0;  // bg_num==0 edge: argsort(all 2.0, stable)[0] == 0
    if (cnum > 0) {
        const int* pref = prefix + (b * 2 + cls) * NB_;
        const int* fl   = fill   + (b * 2 + cls) * NB_;
        // largest j with pref[j] <= rank  (never lands on an empty bucket)
        int lo = 0, hi = NB_ - 1;
        while (lo < hi) {
            int mid = (lo + hi + 1) >> 1;
            if (pref[mid] <= rank) lo = mid; else hi = mid - 1;
        }
        const int bucket = lo;
        const int r      = rank - pref[bucket];
        const int cnt2   = fl[bucket];
        const int*   be  = buckets + (size_t)(b * 2 + cls) * M_ + pref[bucket];
        const float* up  = u_perm + (size_t)b * M_;
        // r-th smallest by (u, idx): stable-argsort semantics, order independent
        for (int t2 = 0; t2 < cnt2; ++t2) {
            int it = be[t2]; float ut = up[it];
            int rk = 0;
            for (int s2 = 0; s2 < cnt2; ++s2) {
                if (s2 == t2) continue;
                int is2 = be[s2]; float us = up[is2];
                if (us < ut || (us == ut && is2 < it)) rk++;
            }
            if (rk == r) { keep = it; break; }
        }
    }

    // gather roi
    float ox1, oy1, ox2, oy2;
    if (keep < N_) {
        const float* p = all_rois + ((size_t)b * N_ + keep) * 5;
        ox1 = p[1]; oy1 = p[2]; ox2 = p[3]; oy2 = p[4];
    } else {
        const float* p = gt_boxes + (b * G_ + (keep - N_)) * 6;
        ox1 = p[0]; oy1 = p[1]; ox2 = p[2]; oy2 = p[3];
    }
    float* ro = out + ((size_t)b * R_ + pos) * 5;
    ro[0] = (float)b; ro[1] = ox1; ro[2] = oy1; ro[3] = ox2; ro[4] = oy2;

    float lab = 0.0f, tidv = -1.0f;
    if (is_fg) {
        int ga = gt_assign[(size_t)b * M_ + keep];
        lab  = gt_boxes[(b * G_ + ga) * 6 + 4];
        tidv = gt_boxes[(b * G_ + ga) * 6 + 5];
    }
    float* olab = out + (size_t)B_ * R_ * 5;
    float* otid = olab + (size_t)B_ * R_;
    olab[b * R_ + pos] = lab;
    otid[b * R_ + pos] = tidv;
}

// ---------------------------------------------------------------------------
extern "C" void kernel_launch(void* const* d_in, const int* in_sizes, int n_in,
                              void* d_out, int out_size, void* d_ws, size_t ws_size,
                              hipStream_t stream)
{
    const float* all_rois = (const float*)d_in[0];
    const float* gt_boxes = (const float*)d_in[1];
    const float* u_perm   = (const float*)d_in[2];
    const float* u_fg     = (const float*)d_in[3];
    const float* u_bg     = (const float*)d_in[4];
    float* out = (float*)d_out;

    // workspace layout (ints unless noted); total ~21 MB
    int* cnt     = (int*)d_ws;                      // 32 (fg/bg totals per b)
    int* hist    = cnt + 32;                        // B*2*NB  (prefix after K2)
    int* fill    = hist + B_ * 2 * NB_;             // B*2*NB
    float* max_ov = (float*)(fill + B_ * 2 * NB_);  // B*M floats
    int* ga      = (int*)(max_ov + (size_t)B_ * M_);// B*M
    int* buckets = ga + (size_t)B_ * M_;            // B*2*M
    float* gtp   = (float*)(buckets + (size_t)B_ * 2 * M_);  // B*5*G floats

    // zero cnt + hist + fill (contiguous at the front)
    size_t zero_bytes = (size_t)(32 + 2 * B_ * 2 * NB_) * sizeof(int);
    hipMemsetAsync(d_ws, 0, zero_bytes, stream);

    prep_kernel<<<(B_ * G_ + 255) / 256, 256, 0, stream>>>(gt_boxes, gtp);

    dim3 grid1((M_ + 255) / 256, B_);
    iou_kernel<<<grid1, 256, 0, stream>>>(all_rois, gt_boxes, gtp, u_perm,
                                          max_ov, ga, hist);
    scan_kernel<<<B_ * 2, 256, 0, stream>>>(hist, cnt);
    scatter_kernel<<<grid1, 256, 0, stream>>>(u_perm, max_ov, hist, fill, buckets);
    sample_kernel<<<16, R_, 0, stream>>>(all_rois, gt_boxes, u_perm, u_fg, u_bg,
                                         cnt, hist, fill, buckets, ga, out);
}

// Round 5
// 141.361 us; speedup vs baseline: 2.3105x; 1.1517x over previous
//
#include <hip/hip_runtime.h>

// Problem constants (match reference)
#define B_   16
#define N_   65536
#define G_   64
#define M_   (N_ + G_)       // 65600 rois per batch (rois + appended gt)
#define R_   128             // ROIS_PER_IMAGE
#define FGP  32              // FG_PER_IMAGE
#define NB_  65536           // buckets for rank selection over u_perm in [0,1)
#define CHUNK_ 2048          // bins per scan chunk
#define NCH_  (NB_ / CHUNK_) // 32 chunks per row
#define NROW_ (B_ * 2)       // 32 (batch, class) rows

// ---------------------------------------------------------------------------
// K0: precompute GT table, SoA [b][5][G]: x1,y1,x2,y2,area with gt_zero folded
//     in as poisoned coords (iw clamps to 0 -> inter==0 -> ov == +0.0 exactly).
// ---------------------------------------------------------------------------
__global__ void prep_kernel(const float* __restrict__ gt_boxes,
                            float* __restrict__ gtp)
{
    int t = blockIdx.x * blockDim.x + threadIdx.x;
    if (t >= B_ * G_) return;
    int b = t / G_, j = t % G_;
    const float* g = gt_boxes + t * 6;
    float x1 = g[0], y1 = g[1], x2 = g[2], y2 = g[3];
    float gw = x2 - x1 + 1.0f, gh = y2 - y1 + 1.0f;
    float area = gw * gh;
    bool gz = (gw == 1.0f) && (gh == 1.0f);
    float* o = gtp + b * 5 * G_;
    o[0 * G_ + j] = gz ?  3.0e8f : x1;
    o[1 * G_ + j] = gz ?  3.0e8f : y1;
    o[2 * G_ + j] = gz ? -3.0e8f : x2;
    o[3 * G_ + j] = gz ? -3.0e8f : y2;
    o[4 * G_ + j] = area;            // =1.0 for gz; denom stays positive
}

// ---------------------------------------------------------------------------
// K1: per-roi IoU max/argmax + fine histogram (no hot-address atomics).
// ---------------------------------------------------------------------------
__global__ void iou_kernel(const float* __restrict__ all_rois,
                           const float* __restrict__ gt_boxes,
                           const float* __restrict__ gtp,
                           const float* __restrict__ u_perm,
                           float* __restrict__ max_ov,
                           int*   __restrict__ gt_assign,
                           int*   __restrict__ hist)
{
    const int b = blockIdx.y;
    const int i = blockIdx.x * blockDim.x + threadIdx.x;
    if (i >= M_) return;

    float x1, y1, x2, y2;
    if (i < N_) {
        const float* p = all_rois + ((size_t)b * N_ + i) * 5;
        x1 = p[1]; y1 = p[2]; x2 = p[3]; y2 = p[4];
    } else {
        const float* p = gt_boxes + (b * G_ + (i - N_)) * 6;
        x1 = p[0]; y1 = p[1]; x2 = p[2]; y2 = p[3];
    }
    float aw = x2 - x1 + 1.0f, ah = y2 - y1 + 1.0f;
    float area_a = aw * ah;
    bool  a_zero = (aw == 1.0f) && (ah == 1.0f);

    const float* gp = gtp + b * 5 * G_;   // block-uniform base -> scalar loads
    float best = -1e30f;
    int   bi   = 0;
    #pragma unroll 16
    for (int j = 0; j < G_; ++j) {
        float iw = fminf(x2, gp[2 * G_ + j]) - fmaxf(x1, gp[0 * G_ + j]) + 1.0f;
        float ih = fminf(y2, gp[3 * G_ + j]) - fmaxf(y1, gp[1 * G_ + j]) + 1.0f;
        iw = fmaxf(iw, 0.0f);
        ih = fmaxf(ih, 0.0f);
        float inter = iw * ih;
        float ov = inter / (area_a + gp[4 * G_ + j] - inter);  // IEEE div
        if (ov > best) { best = ov; bi = j; }                  // first-max
    }
    if (a_zero) { best = -1.0f; bi = 0; }                      // a_zero overrides

    max_ov   [(size_t)b * M_ + i] = best;
    gt_assign[(size_t)b * M_ + i] = bi;

    bool fg = best >= 0.7f;
    bool bg = best < 0.3f;   // == ((mo<0.3)&(mo>=0)) | (mo<0) given mo in {-1}∪[0,1]
    int cls = fg ? 0 : (bg ? 1 : -1);
    if (cls >= 0) {
        float u = u_perm[(size_t)b * M_ + i];
        int bucket = (int)(u * (float)NB_);              // exact pow2 scale, monotone
        bucket = min(max(bucket, 0), NB_ - 1);
        atomicAdd(&hist[(size_t)(b * 2 + cls) * NB_ + bucket], 1);
    }
}

// ---------------------------------------------------------------------------
// K2a: per-chunk sums. grid = (NCH_, NROW_), 256 thr, 8 bins/thread.
// ---------------------------------------------------------------------------
__global__ void sumA_kernel(const int* __restrict__ hist, int* __restrict__ coarse)
{
    __shared__ int red[256];
    const int row = blockIdx.y, ch = blockIdx.x, t = threadIdx.x;
    const int* h = hist + (size_t)row * NB_ + ch * CHUNK_ + t * 8;
    int s = 0;
    #pragma unroll
    for (int k = 0; k < 8; ++k) s += h[k];
    red[t] = s;
    __syncthreads();
    for (int d = 128; d > 0; d >>= 1) {
        if (t < d) red[t] += red[t + d];
        __syncthreads();
    }
    if (t == 0) coarse[row * NCH_ + ch] = red[0];
}

// ---------------------------------------------------------------------------
// K2b: per-row INCLUSIVE scan of the 32 chunk sums (in place) + row totals.
// ---------------------------------------------------------------------------
__global__ void scanB_kernel(int* __restrict__ coarse, int* __restrict__ cnt)
{
    const int t = threadIdx.x;          // 64 threads, rows 0..31 active
    if (t < NROW_) {
        int* c = coarse + t * NCH_;
        int acc = 0;
        for (int k = 0; k < NCH_; ++k) { acc += c[k]; c[k] = acc; }
        cnt[t] = acc;
    }
}

// ---------------------------------------------------------------------------
// K2c: per-chunk exclusive prefix into hist (in place).
//      chunk global exclusive base = coarse_incl[chunk] - chunk_total.
// ---------------------------------------------------------------------------
__global__ void scanC_kernel(int* __restrict__ hist, const int* __restrict__ coarse)
{
    __shared__ int s[256];
    const int row = blockIdx.y, ch = blockIdx.x, t = threadIdx.x;
    int* h = hist + (size_t)row * NB_ + ch * CHUNK_ + t * 8;
    int v[8];
    int mysum = 0;
    #pragma unroll
    for (int k = 0; k < 8; ++k) { v[k] = h[k]; mysum += v[k]; }
    s[t] = mysum;
    __syncthreads();
    // Hillis-Steele inclusive scan over 256 thread sums
    for (int d = 1; d < 256; d <<= 1) {
        int add = (t >= d) ? s[t - d] : 0;
        __syncthreads();
        s[t] += add;
        __syncthreads();
    }
    const int total  = s[255];
    const int texcl  = s[t] - mysum;
    const int gbase  = coarse[row * NCH_ + ch] - total;  // chunk exclusive base
    int run = 0;
    #pragma unroll
    for (int k = 0; k < 8; ++k) { h[k] = gbase + texcl + run; run += v[k]; }
}

// ---------------------------------------------------------------------------
// K3: scatter with destructive prefix: atomicAdd returns the slot; afterwards
//     hist[row][j] == INCLUSIVE prefix (start+count) -- used as-is by K4.
// ---------------------------------------------------------------------------
__global__ void scatter_kernel(const float* __restrict__ u_perm,
                               const float* __restrict__ max_ov,
                               int*        __restrict__ prefix,
                               int*        __restrict__ buckets)
{
    const int b = blockIdx.y;
    const int i = blockIdx.x * blockDim.x + threadIdx.x;
    if (i >= M_) return;
    float mo = max_ov[(size_t)b * M_ + i];
    bool fg = mo >= 0.7f, bg = mo < 0.3f;
    int cls = fg ? 0 : (bg ? 1 : -1);
    if (cls < 0) return;
    float u = u_perm[(size_t)b * M_ + i];
    int bucket = min(max((int)(u * (float)NB_), 0), NB_ - 1);
    int row = b * 2 + cls;
    int p = atomicAdd(&prefix[(size_t)row * NB_ + bucket], 1);
    buckets[(size_t)row * M_ + p] = i;
}

// ---------------------------------------------------------------------------
// K4: per-(batch,pos) rank selection + gather outputs.
//     Coarse row (32 incl sums) in LDS -> 11 dependent global loads max.
// ---------------------------------------------------------------------------
__global__ void sample_kernel(const float* __restrict__ all_rois,
                              const float* __restrict__ gt_boxes,
                              const float* __restrict__ u_perm,
                              const float* __restrict__ u_fg,
                              const float* __restrict__ u_bg,
                              const int*  __restrict__ cnt,
                              const int*  __restrict__ coarse,
                              const int*  __restrict__ prefix,  // inclusive now
                              const int*  __restrict__ buckets,
                              const int*  __restrict__ gt_assign,
                              float*      __restrict__ out)
{
    __shared__ int scoarse[2 * NCH_];   // rows b*2 (fg) and b*2+1 (bg)
    const int b   = blockIdx.x;
    const int pos = threadIdx.x;   // 128 threads
    if (pos < 2 * NCH_) scoarse[pos] = coarse[(b * 2) * NCH_ + pos];
    __syncthreads();

    const int fgn = cnt[b * 2 + 0];
    const int bgn = cnt[b * 2 + 1];
    const bool both    = (fgn > 0) && (bgn > 0);
    const bool only_fg = (fgn > 0) && (bgn == 0);
    const int fg_this  = both ? min(FGP, fgn) : (only_fg ? R_ : 0);
    const bool is_fg   = pos < fg_this;

    int cls, rank, cnum;
    if (is_fg) {
        cls = 0; cnum = fgn;
        if (only_fg) {
            float uf = u_fg[b * R_ + pos];
            int kk = (int)(uf * (float)fgn);               // trunc toward zero
            rank = min(max(kk, 0), max(fgn - 1, 0));
        } else {
            rank = pos;
        }
    } else {
        cls = 1; cnum = bgn;
        float ub = u_bg[b * R_ + pos];
        int kk = (int)(ub * (float)bgn);
        rank = min(max(kk, 0), max(bgn - 1, 0));
    }

    int keep = 0;  // cnum==0 edge: argsort(all 2.0, stable)[0] == 0
    if (cnum > 0) {
        const int row = b * 2 + cls;
        // coarse: first chunk c with incl[c] > rank (exists: incl[NCH-1]=cnum>rank)
        const int* sc = scoarse + cls * NCH_;
        int c = 0;
        while (c < NCH_ - 1 && sc[c] <= rank) ++c;
        // fine: first j in chunk with incl[j] > rank (exists, bucket nonempty)
        const int* pref = prefix + (size_t)row * NB_;
        int lo = c * CHUNK_, hi = c * CHUNK_ + CHUNK_ - 1;
        while (lo < hi) {
            int mid = (lo + hi) >> 1;
            if (pref[mid] > rank) hi = mid; else lo = mid + 1;
        }
        const int j     = lo;
        const int start = (j > 0) ? pref[j - 1] : 0;
        const int cnt2  = pref[j] - start;
        const int r     = rank - start;
        const int*   be = buckets + (size_t)row * M_ + start;
        const float* up = u_perm + (size_t)b * M_;
        // r-th smallest by (u, idx): stable-argsort semantics, order independent
        for (int t2 = 0; t2 < cnt2; ++t2) {
            int it = be[t2]; float ut = up[it];
            int rk = 0;
            for (int s2 = 0; s2 < cnt2; ++s2) {
                if (s2 == t2) continue;
                int is2 = be[s2]; float us = up[is2];
                if (us < ut || (us == ut && is2 < it)) rk++;
            }
            if (rk == r) { keep = it; break; }
        }
    }

    // gather roi
    float ox1, oy1, ox2, oy2;
    if (keep < N_) {
        const float* p = all_rois + ((size_t)b * N_ + keep) * 5;
        ox1 = p[1]; oy1 = p[2]; ox2 = p[3]; oy2 = p[4];
    } else {
        const float* p = gt_boxes + (b * G_ + (keep - N_)) * 6;
        ox1 = p[0]; oy1 = p[1]; ox2 = p[2]; oy2 = p[3];
    }
    float* ro = out + ((size_t)b * R_ + pos) * 5;
    ro[0] = (float)b; ro[1] = ox1; ro[2] = oy1; ro[3] = ox2; ro[4] = oy2;

    float lab = 0.0f, tidv = -1.0f;
    if (is_fg) {
        int ga = gt_assign[(size_t)b * M_ + keep];
        lab  = gt_boxes[(b * G_ + ga) * 6 + 4];
        tidv = gt_boxes[(b * G_ + ga) * 6 + 5];
    }
    float* olab = out + (size_t)B_ * R_ * 5;
    float* otid = olab + (size_t)B_ * R_;
    olab[b * R_ + pos] = lab;
    otid[b * R_ + pos] = tidv;
}

// ---------------------------------------------------------------------------
extern "C" void kernel_launch(void* const* d_in, const int* in_sizes, int n_in,
                              void* d_out, int out_size, void* d_ws, size_t ws_size,
                              hipStream_t stream)
{
    const float* all_rois = (const float*)d_in[0];
    const float* gt_boxes = (const float*)d_in[1];
    const float* u_perm   = (const float*)d_in[2];
    const float* u_fg     = (const float*)d_in[3];
    const float* u_bg     = (const float*)d_in[4];
    float* out = (float*)d_out;

    // workspace layout (4-byte elems); total ~25.3 MB
    int* cnt     = (int*)d_ws;                         // 32
    int* coarse  = cnt + 32;                           // NROW*NCH = 1024
    int* hist    = coarse + NROW_ * NCH_;              // NROW*NB = 2M (excl->incl)
    float* max_ov = (float*)(hist + (size_t)NROW_ * NB_);  // B*M
    int* ga      = (int*)(max_ov + (size_t)B_ * M_);   // B*M
    int* buckets = ga + (size_t)B_ * M_;               // NROW*M
    float* gtp   = (float*)(buckets + (size_t)NROW_ * M_); // B*5*G

    // zero cnt + coarse + hist (contiguous at the front)
    size_t zero_bytes = (size_t)(32 + NROW_ * NCH_ + (size_t)NROW_ * NB_) * sizeof(int);
    hipMemsetAsync(d_ws, 0, zero_bytes, stream);

    prep_kernel<<<(B_ * G_ + 255) / 256, 256, 0, stream>>>(gt_boxes, gtp);

    dim3 grid1((M_ + 255) / 256, B_);
    iou_kernel<<<grid1, 256, 0, stream>>>(all_rois, gt_boxes, gtp, u_perm,
                                          max_ov, ga, hist);

    dim3 grids(NCH_, NROW_);
    sumA_kernel <<<grids, 256, 0, stream>>>(hist, coarse);
    scanB_kernel<<<1, 64, 0, stream>>>(coarse, cnt);
    scanC_kernel<<<grids, 256, 0, stream>>>(hist, coarse);

    scatter_kernel<<<grid1, 256, 0, stream>>>(u_perm, max_ov, hist, buckets);
    sample_kernel<<<16, R_, 0, stream>>>(all_rois, gt_boxes, u_perm, u_fg, u_bg,
                                         cnt, coarse, hist, buckets, ga, out);
}

// Round 6
// 95.742 us; speedup vs baseline: 3.4115x; 1.4765x over previous
//
#include <hip/hip_runtime.h>

// Problem constants (match reference)
#define B_   16
#define N_   65536
#define G_   64
#define M_   (N_ + G_)       // 65600 rois per batch (rois + appended gt)
#define R_   128             // ROIS_PER_IMAGE
#define FGP  32              // FG_PER_IMAGE
#define NB_  16384           // buckets for rank selection over u_perm in [0,1)
#define NCH_ 32              // coarse chunks per row
#define CHUNK_ (NB_ / NCH_)  // 512
#define NROW_ (B_ * 2)       // (batch, class) rows
#define FW_  (NB_ / 32)      // flag words per row = 512

// ---------------------------------------------------------------------------
// K0: GT table, SoA [b][5][G] with gt_zero folded in as poisoned coords
//     (iw clamps to 0 -> inter==0 -> rational q == 0 == reference's masked ov).
// ---------------------------------------------------------------------------
__global__ void prep_kernel(const float* __restrict__ gt_boxes,
                            float* __restrict__ gtp)
{
    int t = blockIdx.x * blockDim.x + threadIdx.x;
    if (t >= B_ * G_) return;
    int b = t / G_, j = t % G_;
    const float* g = gt_boxes + t * 6;
    float x1 = g[0], y1 = g[1], x2 = g[2], y2 = g[3];
    float gw = x2 - x1 + 1.0f, gh = y2 - y1 + 1.0f;
    float area = gw * gh;
    bool gz = (gw == 1.0f) && (gh == 1.0f);
    float* o = gtp + b * 5 * G_;
    o[0 * G_ + j] = gz ?  3.0e8f : x1;
    o[1 * G_ + j] = gz ?  3.0e8f : y1;
    o[2 * G_ + j] = gz ? -3.0e8f : x2;
    o[3 * G_ + j] = gz ? -3.0e8f : y2;
    o[4 * G_ + j] = area;
}

// ---------------------------------------------------------------------------
// K1: divide-free rational max via exact Dekker two-product compare.
//     P1 = inter*ub, P2 = ib*uni; P1 > P2 decided EXACTLY in f32:
//     fl monotone => P1>P2 -> hi1>=hi2; equal-hi => exact residual compare.
//     One IEEE divide per thread at the end -> bit-exact reference max value.
//     Emits packed (cls<<16 | bucket) or ~0; histogram atomic (scattered).
// ---------------------------------------------------------------------------
__global__ void iou_kernel(const float* __restrict__ all_rois,
                           const float* __restrict__ gt_boxes,
                           const float* __restrict__ gtp,
                           const float* __restrict__ u_perm,
                           unsigned*    __restrict__ packed,
                           int*         __restrict__ hist)
{
    const int b = blockIdx.y;
    const int i = blockIdx.x * blockDim.x + threadIdx.x;
    if (i >= M_) return;

    float x1, y1, x2, y2;
    if (i < N_) {
        const float* p = all_rois + ((size_t)b * N_ + i) * 5;
        x1 = p[1]; y1 = p[2]; x2 = p[3]; y2 = p[4];
    } else {
        const float* p = gt_boxes + (b * G_ + (i - N_)) * 6;
        x1 = p[0]; y1 = p[1]; x2 = p[2]; y2 = p[3];
    }
    float aw = x2 - x1 + 1.0f, ah = y2 - y1 + 1.0f;
    float area_a = aw * ah;
    bool  a_zero = (aw == 1.0f) && (ah == 1.0f);

    const float* gp = gtp + b * 5 * G_;   // block-uniform base -> scalar loads
    float ib = 0.0f, ub = 1.0f;           // rational best = 0/1
    #pragma unroll 16
    for (int j = 0; j < G_; ++j) {
        float iw = fminf(x2, gp[2 * G_ + j]) - fmaxf(x1, gp[0 * G_ + j]) + 1.0f;
        float ih = fminf(y2, gp[3 * G_ + j]) - fmaxf(y1, gp[1 * G_ + j]) + 1.0f;
        iw = fmaxf(iw, 0.0f);
        ih = fmaxf(ih, 0.0f);
        float inter = iw * ih;
        float uni   = area_a + gp[4 * G_ + j] - inter;   // > 0 always
        float hi1 = inter * ub;
        float lo1 = fmaf(inter, ub, -hi1);               // exact residual
        float hi2 = ib * uni;
        float lo2 = fmaf(ib, uni, -hi2);                 // exact residual
        bool gt = (hi1 > hi2) || ((hi1 == hi2) && (lo1 > lo2));  // exact P1>P2
        if (gt) { ib = inter; ub = uni; }                // strict >: keeps first
    }
    float best = ib / ub;          // correctly-rounded rational max == ref max
    if (a_zero) best = -1.0f;      // a_zero overrides everything

    bool fg = best >= 0.7f;
    bool bg = best < 0.3f;         // == ((mo<0.3)&(mo>=0)) | (mo<0)
    unsigned pk = 0xFFFFFFFFu;
    if (fg || bg) {
        int cls = fg ? 0 : 1;
        float u = u_perm[(size_t)b * M_ + i];
        int bucket = min(max((int)(u * (float)NB_), 0), NB_ - 1);  // pow2 scale
        pk = ((unsigned)cls << 16) | (unsigned)bucket;
        atomicAdd(&hist[(size_t)(b * 2 + cls) * NB_ + bucket], 1);
    }
    packed[(size_t)b * M_ + i] = pk;
}

// ---------------------------------------------------------------------------
// K2: one block per (batch,class) row: exclusive prefix over 16384 bins,
//     in place, all in registers + 2KB LDS. Emits coarse inclusive chunk sums
//     (32 per row) and the row total (= fg_num / bg_num).
//     512 threads x 32 bins each.
// ---------------------------------------------------------------------------
__global__ void scan_row(int* __restrict__ hist,
                         int* __restrict__ coarse,
                         int* __restrict__ cnt)
{
    __shared__ int bs[512];
    const int row = blockIdx.x, t = threadIdx.x;
    int4* h4 = (int4*)(hist + (size_t)row * NB_ + t * 32);
    int v[32];
    #pragma unroll
    for (int k = 0; k < 8; ++k) {
        int4 x = h4[k];
        v[k * 4 + 0] = x.x; v[k * 4 + 1] = x.y;
        v[k * 4 + 2] = x.z; v[k * 4 + 3] = x.w;
    }
    int run = 0;
    #pragma unroll
    for (int k = 0; k < 32; ++k) { int x = v[k]; v[k] = run; run += x; }
    bs[t] = run;
    __syncthreads();
    for (int d = 1; d < 512; d <<= 1) {   // Hillis-Steele inclusive
        int add = (t >= d) ? bs[t - d] : 0;
        __syncthreads();
        bs[t] += add;
        __syncthreads();
    }
    const int texcl = bs[t] - run;
    if ((t & 15) == 15) coarse[row * NCH_ + (t >> 4)] = bs[t];  // chunk incl
    if (t == 511) cnt[row] = bs[511];
    #pragma unroll
    for (int k = 0; k < 8; ++k) {
        int4 x;
        x.x = v[k * 4 + 0] + texcl; x.y = v[k * 4 + 1] + texcl;
        x.z = v[k * 4 + 2] + texcl; x.w = v[k * 4 + 3] + texcl;
        h4[k] = x;
    }
}

// ---------------------------------------------------------------------------
// K3: per (batch,pos): rank -> bucket (coarse LDS + 9-step binsearch), set
//     bucket's flag bit, store {start, cnt, r} so sample needs no search.
//     Runs while hist is still the pristine EXCLUSIVE prefix.
// ---------------------------------------------------------------------------
__global__ void flag_kernel(const float* __restrict__ u_fg,
                            const float* __restrict__ u_bg,
                            const int*  __restrict__ cnt,
                            const int*  __restrict__ coarse,
                            const int*  __restrict__ E,      // hist (exclusive)
                            unsigned*   __restrict__ flags,
                            int4*       __restrict__ pick)
{
    __shared__ int sc[2 * NCH_];
    const int b = blockIdx.x;
    const int pos = threadIdx.x;    // 128
    if (pos < 2 * NCH_) sc[pos] = coarse[(b * 2) * NCH_ + pos];
    __syncthreads();

    const int fgn = cnt[b * 2 + 0];
    const int bgn = cnt[b * 2 + 1];
    const bool both    = (fgn > 0) && (bgn > 0);
    const bool only_fg = (fgn > 0) && (bgn == 0);
    const int fg_this  = both ? min(FGP, fgn) : (only_fg ? R_ : 0);
    const bool is_fg   = pos < fg_this;

    int cls, rank, cnum;
    if (is_fg) {
        cls = 0; cnum = fgn;
        if (only_fg) {
            float uf = u_fg[b * R_ + pos];
            int kk = (int)(uf * (float)fgn);               // trunc toward zero
            rank = min(max(kk, 0), max(fgn - 1, 0));
        } else {
            rank = pos;
        }
    } else {
        cls = 1; cnum = bgn;
        float ubv = u_bg[b * R_ + pos];
        int kk = (int)(ubv * (float)bgn);
        rank = min(max(kk, 0), max(bgn - 1, 0));
    }

    int4 pk4 = make_int4(0, 0, 0, 0);    // cnt==0 sentinel
    if (cnum > 0) {
        const int row = b * 2 + cls;
        const int* sce = sc + cls * NCH_;
        int c = 0;                        // first chunk with incl > rank
        while (c < NCH_ - 1 && sce[c] <= rank) ++c;
        const int* Er = E + (size_t)row * NB_;
        int lo = c * CHUNK_, hi = c * CHUNK_ + CHUNK_ - 1;
        while (lo < hi) {                 // max j with Er[j] <= rank
            int mid = (lo + hi + 1) >> 1;
            if (Er[mid] <= rank) lo = mid; else hi = mid - 1;
        }
        const int start = Er[lo];
        const int next  = (lo < NB_ - 1) ? Er[lo + 1] : cnum;
        atomicOr(&flags[row * FW_ + (lo >> 5)], 1u << (lo & 31));
        pk4 = make_int4(start, next - start, rank - start, lo);
    }
    pick[b * R_ + pos] = pk4;
}

// ---------------------------------------------------------------------------
// K4: scatter ONLY elements whose bucket is flagged (~0.2%) -> tiny writes.
//     Destructive atomicAdd on E is fine: picks carry start/cnt already.
// ---------------------------------------------------------------------------
__global__ void scatter_kernel(const unsigned* __restrict__ packed,
                               const unsigned* __restrict__ flags,
                               int*            __restrict__ E,
                               int*            __restrict__ buckets)
{
    const int b = blockIdx.y;
    const int i = blockIdx.x * blockDim.x + threadIdx.x;
    if (i >= M_) return;
    unsigned pk = packed[(size_t)b * M_ + i];
    if (pk == 0xFFFFFFFFu) return;
    const int cls = (int)(pk >> 16);
    const int bucket = (int)(pk & 0xFFFFu);
    const int row = b * 2 + cls;
    unsigned w = flags[row * FW_ + (bucket >> 5)];     // 64KB table: L2-hot
    if (!(w & (1u << (bucket & 31)))) return;
    int p = atomicAdd(&E[(size_t)row * NB_ + bucket], 1);
    buckets[(size_t)row * M_ + p] = i;
}

// ---------------------------------------------------------------------------
// K5: selection among the <=~16 bucket members by (u, idx) stable rank,
//     gather outputs, and LAZY argmax (reference divide semantics) for the
//     <=2048 picked fg rois only.
// ---------------------------------------------------------------------------
__global__ void sample_kernel(const float* __restrict__ all_rois,
                              const float* __restrict__ gt_boxes,
                              const float* __restrict__ gtp,
                              const float* __restrict__ u_perm,
                              const int*  __restrict__ cnt,
                              const int4* __restrict__ pick,
                              const int*  __restrict__ buckets,
                              float*      __restrict__ out)
{
    const int b   = blockIdx.x;
    const int pos = threadIdx.x;   // 128
    const int fgn = cnt[b * 2 + 0];
    const int bgn = cnt[b * 2 + 1];
    const bool both    = (fgn > 0) && (bgn > 0);
    const bool only_fg = (fgn > 0) && (bgn == 0);
    const int fg_this  = both ? min(FGP, fgn) : (only_fg ? R_ : 0);
    const bool is_fg   = pos < fg_this;
    const int cls  = is_fg ? 0 : 1;

    const int4 pk = pick[b * R_ + pos];
    int keep = 0;                  // cnum==0 edge: argsort(all 2.0)[0] == 0
    if (pk.y > 0) {
        const int row = b * 2 + cls;
        const int*   be = buckets + (size_t)row * M_ + pk.x;
        const float* up = u_perm + (size_t)b * M_;
        const int cnt2 = pk.y, r = pk.z;
        for (int t2 = 0; t2 < cnt2; ++t2) {
            int it = be[t2]; float ut = up[it];
            int rk = 0;
            for (int s2 = 0; s2 < cnt2; ++s2) {
                if (s2 == t2) continue;
                int is2 = be[s2]; float us = up[is2];
                if (us < ut || (us == ut && is2 < it)) rk++;
            }
            if (rk == r) { keep = it; break; }
        }
    }

    // gather roi coords
    float ox1, oy1, ox2, oy2;
    if (keep < N_) {
        const float* p = all_rois + ((size_t)b * N_ + keep) * 5;
        ox1 = p[1]; oy1 = p[2]; ox2 = p[3]; oy2 = p[4];
    } else {
        const float* p = gt_boxes + (b * G_ + (keep - N_)) * 6;
        ox1 = p[0]; oy1 = p[1]; ox2 = p[2]; oy2 = p[3];
    }
    float* ro = out + ((size_t)b * R_ + pos) * 5;
    ro[0] = (float)b; ro[1] = ox1; ro[2] = oy1; ro[3] = ox2; ro[4] = oy2;

    // lazy argmax with exact reference semantics (fg picks only)
    float lab = 0.0f, tidv = -1.0f;
    if (is_fg) {
        float aw = ox2 - ox1 + 1.0f, ah = oy2 - oy1 + 1.0f;
        float area_a = aw * ah;
        const float* gp = gtp + b * 5 * G_;
        float best = -1e30f;
        int   bi   = 0;
        for (int j = 0; j < G_; ++j) {
            float iw = fminf(ox2, gp[2 * G_ + j]) - fmaxf(ox1, gp[0 * G_ + j]) + 1.0f;
            float ih = fminf(oy2, gp[3 * G_ + j]) - fmaxf(oy1, gp[1 * G_ + j]) + 1.0f;
            iw = fmaxf(iw, 0.0f);
            ih = fmaxf(ih, 0.0f);
            float inter = iw * ih;
            float ov = inter / (area_a + gp[4 * G_ + j] - inter);  // IEEE div
            if (ov > best) { best = ov; bi = j; }                  // first-max
        }
        lab  = gt_boxes[(b * G_ + bi) * 6 + 4];
        tidv = gt_boxes[(b * G_ + bi) * 6 + 5];
    }
    float* olab = out + (size_t)B_ * R_ * 5;
    float* otid = olab + (size_t)B_ * R_;
    olab[b * R_ + pos] = lab;
    otid[b * R_ + pos] = tidv;
}

// ---------------------------------------------------------------------------
extern "C" void kernel_launch(void* const* d_in, const int* in_sizes, int n_in,
                              void* d_out, int out_size, void* d_ws, size_t ws_size,
                              hipStream_t stream)
{
    const float* all_rois = (const float*)d_in[0];
    const float* gt_boxes = (const float*)d_in[1];
    const float* u_perm   = (const float*)d_in[2];
    const float* u_fg     = (const float*)d_in[3];
    const float* u_bg     = (const float*)d_in[4];
    float* out = (float*)d_out;

    // workspace layout (4B elems); ~15 MB total
    int*      hist    = (int*)d_ws;                          // NROW*NB = 512K
    unsigned* flags   = (unsigned*)(hist + (size_t)NROW_ * NB_);  // NROW*FW = 16K
    int*      cnt     = (int*)(flags + NROW_ * FW_);         // 32
    int*      coarse  = cnt + 32;                            // NROW*NCH = 1024
    int4*     pick    = (int4*)(coarse + NROW_ * NCH_);      // B*R int4
    unsigned* packed  = (unsigned*)(pick + B_ * R_);         // B*M
    int*      buckets = (int*)(packed + (size_t)B_ * M_);    // NROW*M
    float*    gtp     = (float*)(buckets + (size_t)NROW_ * M_);  // B*5*G

    // zero hist + flags (contiguous)
    hipMemsetAsync(d_ws, 0, (size_t)(NROW_ * NB_ + NROW_ * FW_) * sizeof(int), stream);

    prep_kernel<<<(B_ * G_ + 255) / 256, 256, 0, stream>>>(gt_boxes, gtp);

    dim3 grid1((M_ + 255) / 256, B_);
    iou_kernel<<<grid1, 256, 0, stream>>>(all_rois, gt_boxes, gtp, u_perm,
                                          packed, hist);
    scan_row<<<NROW_, 512, 0, stream>>>(hist, coarse, cnt);
    flag_kernel<<<B_, R_, 0, stream>>>(u_fg, u_bg, cnt, coarse, hist, flags, pick);
    scatter_kernel<<<grid1, 256, 0, stream>>>(packed, flags, hist, buckets);
    sample_kernel<<<B_, R_, 0, stream>>>(all_rois, gt_boxes, gtp, u_perm,
                                         cnt, pick, buckets, out);
}